// Round 3
// baseline (2312.891 us; speedup 1.0000x reference)
//
#include <hip/hip_runtime.h>

#define N_NODES 100000
#define N_EDGES 1600000

typedef unsigned int u32;
typedef unsigned short u16;

__device__ __forceinline__ float bf2f(u16 u){ return __uint_as_float(((u32)u) << 16); }
__device__ __forceinline__ float lo16(u32 u){ return __uint_as_float(u << 16); }
__device__ __forceinline__ float hi16(u32 u){ return __uint_as_float(u & 0xffff0000u); }
__device__ __forceinline__ u32 f2bfbits(float f){
  u32 u = __float_as_uint(f);
  return (u + 0x7fffu + ((u >> 16) & 1u)) >> 16;
}
// monotonic float<->uint mapping for atomicMax (init 0 == -inf sentinel)
__device__ __forceinline__ u32 flipf(float f){
  u32 u = __float_as_uint(f);
  return (u & 0x80000000u) ? ~u : (u | 0x80000000u);
}
__device__ __forceinline__ float unflipf(u32 u){
  return __uint_as_float((u & 0x80000000u) ? (u & 0x7fffffffu) : ~u);
}

// DT=1: fp32 buffers, DT=0: bf16 buffers
template<int DT>
__device__ __forceinline__ float ldf(const void* p, size_t i){
  if (DT) return ((const float*)p)[i];
  else    return bf2f(((const u16*)p)[i]);
}

// flags[0]: 1 if edge_index is int64, 0 if int32
// flags[1]: 1 if float tensors are fp32, 0 if bf16
__device__ __forceinline__ int ld_src(const int* ei, int e, int f64){
  return f64 ? ei[2*(size_t)e] : ei[e];
}
__device__ __forceinline__ int ld_tgt(const int* ei, int e, int f64){
  return f64 ? ei[2*((size_t)N_EDGES + (size_t)e)] : ei[(size_t)N_EDGES + e];
}

extern "C" __global__ void detect_kernel(const int* __restrict__ ei,
                                         const u32* __restrict__ xw,
                                         int* __restrict__ flags)
{
  if (blockIdx.x == 0 && threadIdx.x == 0) {
    // int64 detection: odd 32-bit words of src row are all 0 for int64 (<2^31 values)
    int any = 0;
    #pragma unroll
    for (int i = 0; i < 32; ++i) any |= ei[2*i + 1];
    flags[0] = (any == 0) ? 1 : 0;
    // dtype detection: if x is fp32, its low 16-bit halves are random mantissa
    // bits -> decoded as bf16 they frequently exceed 1024 (or NaN). True bf16
    // N(0,1) data never does.
    int weird = 0;
    for (int i = 0; i < 256; ++i) {
      u32 w = xw[i];
      float a = lo16(w), b = hi16(w);
      if (!(fabsf(a) < 1024.f)) weird++;
      if (!(fabsf(b) < 1024.f)) weird++;
    }
    flags[1] = (weird > 0) ? 1 : 0;
  }
}

// ---------------- K1: QKV projection (x @ W -> bf16 in scratch) -------------
// grid (ceil(N/64), 3), block 256. Dual-compiled; self-gates on flags[1].
template<int DT>
__global__ __launch_bounds__(256) void qkv_gemm_t(
    const void* __restrict__ x, const void* __restrict__ Wq,
    const void* __restrict__ Wk, const void* __restrict__ Wv,
    u16* __restrict__ Q, u16* __restrict__ Kd, u16* __restrict__ Vd,
    const int* __restrict__ flags)
{
  if (flags[1] != DT) return;
  __shared__ float xs[64*129];
  const int tid = threadIdx.x;
  const int row0 = blockIdx.x * 64;
  const void* W = (blockIdx.y == 0) ? Wq : (blockIdx.y == 1) ? Wk : Wv;
  u16* Out = (blockIdx.y == 0) ? Q : (blockIdx.y == 1) ? Kd : Vd;

  if (DT) {
    const float4* xg = (const float4*)x;
    #pragma unroll
    for (int i = 0; i < 8; ++i) {
      int li = tid + i*256;           // 64 rows x 32 float4
      int r = li >> 5, c4 = li & 31;
      float4 v = make_float4(0.f,0.f,0.f,0.f);
      if (row0 + r < N_NODES) v = xg[(size_t)(row0 + r)*32 + c4];
      int base = r*129 + c4*4;
      xs[base] = v.x; xs[base+1] = v.y; xs[base+2] = v.z; xs[base+3] = v.w;
    }
  } else {
    const uint4* xg = (const uint4*)x;  // 8 bf16 per uint4; 16 per row
    #pragma unroll
    for (int i = 0; i < 4; ++i) {
      int li = tid + i*256;           // 64 rows x 16 uint4
      int r = li >> 4, c8 = li & 15;
      uint4 v = make_uint4(0,0,0,0);
      if (row0 + r < N_NODES) v = xg[(size_t)(row0 + r)*16 + c8];
      int base = r*129 + c8*8;
      xs[base+0]=lo16(v.x); xs[base+1]=hi16(v.x);
      xs[base+2]=lo16(v.y); xs[base+3]=hi16(v.y);
      xs[base+4]=lo16(v.z); xs[base+5]=hi16(v.z);
      xs[base+6]=lo16(v.w); xs[base+7]=hi16(v.w);
    }
  }
  __syncthreads();

  const int cg = tid & 31;        // cols cg*4..+3
  const int r0 = (tid >> 5) * 8;  // 8 rows per thread
  float acc[8][4];
  #pragma unroll
  for (int i=0;i<8;++i){ acc[i][0]=0.f; acc[i][1]=0.f; acc[i][2]=0.f; acc[i][3]=0.f; }

  for (int k = 0; k < 128; ++k) {
    float4 b;
    if (DT) {
      b = ((const float4*)W)[k*32 + cg];
    } else {
      uint2 t = ((const uint2*)W)[k*32 + cg];
      b = make_float4(lo16(t.x), hi16(t.x), lo16(t.y), hi16(t.y));
    }
    #pragma unroll
    for (int i = 0; i < 8; ++i) {
      float a = xs[(r0+i)*129 + k];
      acc[i][0] += a*b.x; acc[i][1] += a*b.y; acc[i][2] += a*b.z; acc[i][3] += a*b.w;
    }
  }
  #pragma unroll
  for (int i = 0; i < 8; ++i) {
    int gr = row0 + r0 + i;
    if (gr < N_NODES) {
      u32 p0 = f2bfbits(acc[i][0]) | (f2bfbits(acc[i][1]) << 16);
      u32 p1 = f2bfbits(acc[i][2]) | (f2bfbits(acc[i][3]) << 16);
      ((uint2*)(Out + (size_t)gr*128))[cg] = make_uint2(p0, p1);
    }
  }
}

// -------- K2: per-edge MLP bias + QK dot scores + seg_max atomics ----------
template<int DT>
__global__ __launch_bounds__(256) void edge_kernel_t(
    const int* __restrict__ ei, const void* __restrict__ ea,
    const void* __restrict__ We1, const void* __restrict__ be1,
    const void* __restrict__ We2, const void* __restrict__ be2,
    const u16* __restrict__ Q, const u16* __restrict__ Kd,
    float* __restrict__ scores, u32* __restrict__ seg_max,
    const int* __restrict__ flags)
{
  if (flags[1] != DT) return;
  __shared__ __align__(16) float wpk[128][16]; // {be1, We1[0..5][j], pad, We2[j][0..7]}
  __shared__ float b2s[8];
  const int tid = threadIdx.x;
  if (tid < 128) {
    int j = tid;
    wpk[j][0] = ldf<DT>(be1, j);
    #pragma unroll
    for (int d = 0; d < 6; ++d) wpk[j][1+d] = ldf<DT>(We1, d*128 + j);
    wpk[j][7] = 0.f;
    #pragma unroll
    for (int h = 0; h < 8; ++h) wpk[j][8+h] = ldf<DT>(We2, j*8 + h);
  }
  if (tid < 8) b2s[tid] = ldf<DT>(be2, tid);
  __syncthreads();

  const int gid = blockIdx.x * 256 + tid;
  if (gid >= N_EDGES/4) return;
  const int e0 = gid * 4;
  const int f64 = flags[0];

  float4 av[6];
  float* a = (float*)av;
  if (DT) {
    const float4* eg = (const float4*)ea + (size_t)gid*6;  // 4 edges x 6 f32
    #pragma unroll
    for (int i = 0; i < 6; ++i) av[i] = eg[i];
  } else {
    const uint4* eg = (const uint4*)ea + (size_t)gid*3;    // 24 bf16
    uint4 v0 = eg[0], v1 = eg[1], v2 = eg[2];
    u32 d[12] = {v0.x,v0.y,v0.z,v0.w, v1.x,v1.y,v1.z,v1.w, v2.x,v2.y,v2.z,v2.w};
    #pragma unroll
    for (int idx = 0; idx < 24; ++idx)
      a[idx] = (idx & 1) ? hi16(d[idx >> 1]) : lo16(d[idx >> 1]);
  }

  float bias[4][8];
  #pragma unroll
  for (int t=0;t<4;++t)
    #pragma unroll
    for (int h=0;h<8;++h) bias[t][h] = b2s[h];

  for (int j = 0; j < 128; ++j) {
    const float4* wp = (const float4*)wpk[j];
    float4 p0 = wp[0], p1 = wp[1], p2 = wp[2], p3 = wp[3];
    #pragma unroll
    for (int t = 0; t < 4; ++t) {
      float h = p0.x + a[t*6+0]*p0.y + a[t*6+1]*p0.z + a[t*6+2]*p0.w
                     + a[t*6+3]*p1.x + a[t*6+4]*p1.y + a[t*6+5]*p1.z;
      float g = 0.5f * h * (1.0f + erff(h * 0.70710678118654752f)); // exact GELU
      bias[t][0] += g*p2.x; bias[t][1] += g*p2.y; bias[t][2] += g*p2.z; bias[t][3] += g*p2.w;
      bias[t][4] += g*p3.x; bias[t][5] += g*p3.y; bias[t][6] += g*p3.z; bias[t][7] += g*p3.w;
    }
  }

  #pragma unroll
  for (int t = 0; t < 4; ++t) {
    int e = e0 + t;
    int src = ld_src(ei, e, f64);
    int tgt = ld_tgt(ei, e, f64);
    const uint4* qr = (const uint4*)(Q  + (size_t)tgt*128);
    const uint4* kr = (const uint4*)(Kd + (size_t)src*128);
    float sc[8];
    #pragma unroll
    for (int hh = 0; hh < 8; ++hh) {
      uint4 qa = qr[hh*2], qb = qr[hh*2+1];
      uint4 ka = kr[hh*2], kb = kr[hh*2+1];
      float s = 0.f;
      s += lo16(qa.x)*lo16(ka.x) + hi16(qa.x)*hi16(ka.x);
      s += lo16(qa.y)*lo16(ka.y) + hi16(qa.y)*hi16(ka.y);
      s += lo16(qa.z)*lo16(ka.z) + hi16(qa.z)*hi16(ka.z);
      s += lo16(qa.w)*lo16(ka.w) + hi16(qa.w)*hi16(ka.w);
      s += lo16(qb.x)*lo16(kb.x) + hi16(qb.x)*hi16(kb.x);
      s += lo16(qb.y)*lo16(kb.y) + hi16(qb.y)*hi16(kb.y);
      s += lo16(qb.z)*lo16(kb.z) + hi16(qb.z)*hi16(kb.z);
      s += lo16(qb.w)*lo16(kb.w) + hi16(qb.w)*hi16(kb.w);
      sc[hh] = s * 0.25f + bias[t][hh];
    }
    float4* so = (float4*)(scores + (size_t)e*8);
    so[0] = make_float4(sc[0],sc[1],sc[2],sc[3]);
    so[1] = make_float4(sc[4],sc[5],sc[6],sc[7]);
    u32* sm = seg_max + (size_t)tgt*8;
    #pragma unroll
    for (int hh = 0; hh < 8; ++hh) atomicMax(&sm[hh], flipf(sc[hh]));
  }
}

// ---------------- K3: exp(score - segmax) in place + segment sum ------------
extern "C" __global__ __launch_bounds__(256) void exp_sum_kernel(
    const int* __restrict__ ei, float* __restrict__ scores,
    const u32* __restrict__ seg_max, float* __restrict__ seg_sum,
    const int* __restrict__ flags)
{
  int e = blockIdx.x*256 + threadIdx.x;
  if (e >= N_EDGES) return;
  int t = ld_tgt(ei, e, flags[0]);
  float4 s0 = ((float4*)(scores + (size_t)e*8))[0];
  float4 s1 = ((float4*)(scores + (size_t)e*8))[1];
  const u32* sm = seg_max + (size_t)t*8;
  float m[8];
  #pragma unroll
  for (int h=0; h<8; ++h) m[h] = unflipf(sm[h]);
  float ex[8] = { __expf(s0.x-m[0]), __expf(s0.y-m[1]), __expf(s0.z-m[2]), __expf(s0.w-m[3]),
                  __expf(s1.x-m[4]), __expf(s1.y-m[5]), __expf(s1.z-m[6]), __expf(s1.w-m[7]) };
  ((float4*)(scores + (size_t)e*8))[0] = make_float4(ex[0],ex[1],ex[2],ex[3]);
  ((float4*)(scores + (size_t)e*8))[1] = make_float4(ex[4],ex[5],ex[6],ex[7]);
  float* ss = seg_sum + (size_t)t*8;
  #pragma unroll
  for (int h=0; h<8; ++h) atomicAdd(&ss[h], ex[h]);
}

// ------------- K4: normalize -> attn_weights into d_out (bf16 or fp32) ------
extern "C" __global__ __launch_bounds__(256) void normalize_kernel(
    const int* __restrict__ ei, const float* __restrict__ scores,
    const float* __restrict__ seg_sum, void* __restrict__ dout,
    const int* __restrict__ flags)
{
  size_t i = (size_t)blockIdx.x*256 + threadIdx.x;   // over E*8 = 12.8M
  if (i >= (size_t)N_EDGES*8) return;
  int e = (int)(i >> 3), h = (int)(i & 7);
  int t = ld_tgt(ei, e, flags[0]);
  float w = scores[i] / seg_sum[(size_t)t*8 + h];
  size_t base = (size_t)N_NODES*128;
  if (flags[1]) ((float*)dout)[base + i] = w;
  else          ((u16*)dout)[base + i] = (u16)f2bfbits(w);
}

// ------------- K5: scatter w * V[src] into out_acc[tgt] (wave/edge) ---------
extern "C" __global__ __launch_bounds__(256) void scatter_kernel(
    const int* __restrict__ ei, const void* __restrict__ dout,
    const u16* __restrict__ Vd, float* __restrict__ out_acc,
    const int* __restrict__ flags)
{
  int gid = blockIdx.x*256 + threadIdx.x;
  int e = gid >> 6;
  int lane = gid & 63;
  if (e >= N_EDGES) return;
  int f64 = flags[0], dt = flags[1];
  int s = ld_src(ei, e, f64), t = ld_tgt(ei, e, f64);
  int h0 = lane >> 4;
  size_t base = (size_t)N_NODES*128 + (size_t)e*8;
  float w0, w1;
  if (dt) { const float* aw = (const float*)dout; w0 = aw[base+h0]; w1 = aw[base+h0+4]; }
  else    { const u16*   aw = (const u16*)dout;   w0 = bf2f(aw[base+h0]); w1 = bf2f(aw[base+h0+4]); }
  float v0 = bf2f(Vd[(size_t)s*128 + lane]);
  float v1 = bf2f(Vd[(size_t)s*128 + lane + 64]);
  atomicAdd(&out_acc[(size_t)t*128 + lane], w0*v0);
  atomicAdd(&out_acc[(size_t)t*128 + lane + 64], w1*v1);
}

// ---------------- K6: output projection (fp32 acc @ Wo + bo -> d_out) -------
template<int DT>
__global__ __launch_bounds__(256) void out_proj_t(
    const float* __restrict__ acc_in, const void* __restrict__ Wo,
    const void* __restrict__ bo, void* __restrict__ dout,
    const int* __restrict__ flags)
{
  if (flags[1] != DT) return;
  __shared__ float as_[64*129];
  const int tid = threadIdx.x;
  const int row0 = blockIdx.x * 64;
  {
    const float4* ag = (const float4*)acc_in;
    #pragma unroll
    for (int i = 0; i < 8; ++i) {
      int li = tid + i*256;           // 64 rows x 32 float4
      int r = li >> 5, c4 = li & 31;
      float4 v = make_float4(0.f,0.f,0.f,0.f);
      if (row0 + r < N_NODES) v = ag[(size_t)(row0 + r)*32 + c4];
      int base = r*129 + c4*4;
      as_[base] = v.x; as_[base+1] = v.y; as_[base+2] = v.z; as_[base+3] = v.w;
    }
  }
  __syncthreads();
  const int cg = tid & 31;
  const int r0 = (tid >> 5) * 8;
  float acc[8][4];
  #pragma unroll
  for (int i=0;i<8;++i){ acc[i][0]=0.f; acc[i][1]=0.f; acc[i][2]=0.f; acc[i][3]=0.f; }

  for (int k = 0; k < 128; ++k) {
    float4 b;
    if (DT) {
      b = ((const float4*)Wo)[k*32 + cg];
    } else {
      uint2 t = ((const uint2*)Wo)[k*32 + cg];
      b = make_float4(lo16(t.x), hi16(t.x), lo16(t.y), hi16(t.y));
    }
    #pragma unroll
    for (int i = 0; i < 8; ++i) {
      float a = as_[(r0+i)*129 + k];
      acc[i][0] += a*b.x; acc[i][1] += a*b.y; acc[i][2] += a*b.z; acc[i][3] += a*b.w;
    }
  }
  float bb0 = ldf<DT>(bo, cg*4+0), bb1 = ldf<DT>(bo, cg*4+1);
  float bb2 = ldf<DT>(bo, cg*4+2), bb3 = ldf<DT>(bo, cg*4+3);
  #pragma unroll
  for (int i = 0; i < 8; ++i) {
    int gr = row0 + r0 + i;
    if (gr < N_NODES) {
      if (DT) {
        ((float4*)((float*)dout + (size_t)gr*128))[cg] =
            make_float4(acc[i][0]+bb0, acc[i][1]+bb1, acc[i][2]+bb2, acc[i][3]+bb3);
      } else {
        u32 p0 = f2bfbits(acc[i][0]+bb0) | (f2bfbits(acc[i][1]+bb1) << 16);
        u32 p1 = f2bfbits(acc[i][2]+bb2) | (f2bfbits(acc[i][3]+bb3) << 16);
        ((uint2*)((u16*)dout + (size_t)gr*128))[cg] = make_uint2(p0, p1);
      }
    }
  }
}

extern "C" void kernel_launch(void* const* d_in, const int* in_sizes, int n_in,
                              void* d_out, int out_size, void* d_ws, size_t ws_size,
                              hipStream_t stream)
{
  const void* x   = d_in[0];
  const int*  ei  = (const int*)d_in[1];
  const void* ea  = d_in[2];
  const void* Wq  = d_in[3];
  const void* Wk  = d_in[4];
  const void* Wv  = d_in[5];
  const void* We1 = d_in[6];
  const void* be1 = d_in[7];
  const void* We2 = d_in[8];
  const void* be2 = d_in[9];
  const void* Wo  = d_in[10];
  const void* bo  = d_in[11];

  // ws layout (83.2 MB total -- safe under a 128 MiB workspace):
  char* ws = (char*)d_ws;
  int*   flags   = (int*)  ws;                  // 8 B
  u16*   Vd      = (u16*)  (ws + 4096);         // N*128 bf16 = 25.6 MB
  float* scores  = (float*)(ws + 25604096);     // E*8 f32 = 51.2 MB (reused as out_acc)
  u32*   seg_max = (u32*)  (ws + 76804096);     // N*8 u32 = 3.2 MB
  float* seg_sum = (float*)(ws + 80004096);     // N*8 f32 = 3.2 MB -> ends 83,204,096
  float* out_acc = scores;

  // Q/K staged in d_out's dead regions (bf16, 25.6 MB each):
  //  - Q in the final-out region (overwritten last by out_proj)
  //  - K in the attn region for bf16 out (overwritten by normalize AFTER K is dead);
  //    for fp32 out the attn region starts at byte 51.2MB so no overlap at all.
  u16* Q  = (u16*)d_out;
  u16* Kd = Q + (size_t)N_NODES*128;

  detect_kernel<<<dim3(1), 64, 0, stream>>>(ei, (const u32*)x, flags);
  hipMemsetAsync(seg_max, 0, 6400000, stream);   // seg_max (flip -inf == 0) + seg_sum

  qkv_gemm_t<0><<<dim3(1563,3), 256, 0, stream>>>(x, Wq, Wk, Wv, Q, Kd, Vd, flags);
  qkv_gemm_t<1><<<dim3(1563,3), 256, 0, stream>>>(x, Wq, Wk, Wv, Q, Kd, Vd, flags);
  edge_kernel_t<0><<<dim3(1563), 256, 0, stream>>>(ei, ea, We1, be1, We2, be2, Q, Kd, scores, seg_max, flags);
  edge_kernel_t<1><<<dim3(1563), 256, 0, stream>>>(ei, ea, We1, be1, We2, be2, Q, Kd, scores, seg_max, flags);
  exp_sum_kernel<<<dim3(6250), 256, 0, stream>>>(ei, scores, seg_max, seg_sum, flags);
  normalize_kernel<<<dim3(50000), 256, 0, stream>>>(ei, scores, seg_sum, d_out, flags);
  // scores region is now dead -> becomes the fp32 output accumulator
  hipMemsetAsync(out_acc, 0, 51200000, stream);
  scatter_kernel<<<dim3(400000), 256, 0, stream>>>(ei, d_out, Vd, out_acc, flags);
  out_proj_t<0><<<dim3(1563), 256, 0, stream>>>(out_acc, Wo, bo, d_out, flags);
  out_proj_t<1><<<dim3(1563), 256, 0, stream>>>(out_acc, Wo, bo, d_out, flags);
}

// Round 4
// 1208.875 us; speedup vs baseline: 1.9133x; 1.9133x over previous
//
#include <hip/hip_runtime.h>

#define N_NODES 100000
#define N_EDGES 1600000

typedef unsigned int u32;
typedef unsigned short u16;

__device__ __forceinline__ float bf2f(u16 u){ return __uint_as_float(((u32)u) << 16); }
__device__ __forceinline__ float lo16(u32 u){ return __uint_as_float(u << 16); }
__device__ __forceinline__ float hi16(u32 u){ return __uint_as_float(u & 0xffff0000u); }
__device__ __forceinline__ u32 f2bfbits(float f){
  u32 u = __float_as_uint(f);
  return (u + 0x7fffu + ((u >> 16) & 1u)) >> 16;
}

// DT=1: fp32 buffers, DT=0: bf16 buffers
template<int DT>
__device__ __forceinline__ float ldf(const void* p, size_t i){
  if (DT) return ((const float*)p)[i];
  else    return bf2f(((const u16*)p)[i]);
}

// flags[0]: 1 if edge_index is int64, 0 if int32
// flags[1]: 1 if float tensors are fp32, 0 if bf16
__device__ __forceinline__ int ld_src(const int* ei, int e, int f64){
  return f64 ? ei[2*(size_t)e] : ei[e];
}
__device__ __forceinline__ int ld_tgt(const int* ei, int e, int f64){
  return f64 ? ei[2*((size_t)N_EDGES + (size_t)e)] : ei[(size_t)N_EDGES + e];
}

extern "C" __global__ void detect_kernel(const int* __restrict__ ei,
                                         const u32* __restrict__ xw,
                                         int* __restrict__ flags)
{
  if (blockIdx.x == 0 && threadIdx.x == 0) {
    int any = 0;
    #pragma unroll
    for (int i = 0; i < 32; ++i) any |= ei[2*i + 1];
    flags[0] = (any == 0) ? 1 : 0;
    int weird = 0;
    for (int i = 0; i < 256; ++i) {
      u32 w = xw[i];
      float a = lo16(w), b = hi16(w);
      if (!(fabsf(a) < 1024.f)) weird++;
      if (!(fabsf(b) < 1024.f)) weird++;
    }
    flags[1] = (weird > 0) ? 1 : 0;
  }
}

// ---------------- K1: QKV projection (x @ W -> bf16) ------------------------
template<int DT>
__global__ __launch_bounds__(256) void qkv_gemm_t(
    const void* __restrict__ x, const void* __restrict__ Wq,
    const void* __restrict__ Wk, const void* __restrict__ Wv,
    u16* __restrict__ Q, u16* __restrict__ Kd, u16* __restrict__ Vd,
    const int* __restrict__ flags)
{
  if (flags[1] != DT) return;
  __shared__ float xs[64*129];
  const int tid = threadIdx.x;
  const int row0 = blockIdx.x * 64;
  const void* W = (blockIdx.y == 0) ? Wq : (blockIdx.y == 1) ? Wk : Wv;
  u16* Out = (blockIdx.y == 0) ? Q : (blockIdx.y == 1) ? Kd : Vd;

  if (DT) {
    const float4* xg = (const float4*)x;
    #pragma unroll
    for (int i = 0; i < 8; ++i) {
      int li = tid + i*256;           // 64 rows x 32 float4
      int r = li >> 5, c4 = li & 31;
      float4 v = make_float4(0.f,0.f,0.f,0.f);
      if (row0 + r < N_NODES) v = xg[(size_t)(row0 + r)*32 + c4];
      int base = r*129 + c4*4;
      xs[base] = v.x; xs[base+1] = v.y; xs[base+2] = v.z; xs[base+3] = v.w;
    }
  } else {
    const uint4* xg = (const uint4*)x;
    #pragma unroll
    for (int i = 0; i < 4; ++i) {
      int li = tid + i*256;           // 64 rows x 16 uint4
      int r = li >> 4, c8 = li & 15;
      uint4 v = make_uint4(0,0,0,0);
      if (row0 + r < N_NODES) v = xg[(size_t)(row0 + r)*16 + c8];
      int base = r*129 + c8*8;
      xs[base+0]=lo16(v.x); xs[base+1]=hi16(v.x);
      xs[base+2]=lo16(v.y); xs[base+3]=hi16(v.y);
      xs[base+4]=lo16(v.z); xs[base+5]=hi16(v.z);
      xs[base+6]=lo16(v.w); xs[base+7]=hi16(v.w);
    }
  }
  __syncthreads();

  const int cg = tid & 31;
  const int r0 = (tid >> 5) * 8;
  float acc[8][4];
  #pragma unroll
  for (int i=0;i<8;++i){ acc[i][0]=0.f; acc[i][1]=0.f; acc[i][2]=0.f; acc[i][3]=0.f; }

  for (int k = 0; k < 128; ++k) {
    float4 b;
    if (DT) {
      b = ((const float4*)W)[k*32 + cg];
    } else {
      uint2 t = ((const uint2*)W)[k*32 + cg];
      b = make_float4(lo16(t.x), hi16(t.x), lo16(t.y), hi16(t.y));
    }
    #pragma unroll
    for (int i = 0; i < 8; ++i) {
      float a = xs[(r0+i)*129 + k];
      acc[i][0] += a*b.x; acc[i][1] += a*b.y; acc[i][2] += a*b.z; acc[i][3] += a*b.w;
    }
  }
  #pragma unroll
  for (int i = 0; i < 8; ++i) {
    int gr = row0 + r0 + i;
    if (gr < N_NODES) {
      u32 p0 = f2bfbits(acc[i][0]) | (f2bfbits(acc[i][1]) << 16);
      u32 p1 = f2bfbits(acc[i][2]) | (f2bfbits(acc[i][3]) << 16);
      ((uint2*)(Out + (size_t)gr*128))[cg] = make_uint2(p0, p1);
    }
  }
}

// -------- K2: per-edge MLP bias + QK dot -> raw scores (NO atomics) ---------
template<int DT>
__global__ __launch_bounds__(256) void edge_kernel_t(
    const int* __restrict__ ei, const void* __restrict__ ea,
    const void* __restrict__ We1, const void* __restrict__ be1,
    const void* __restrict__ We2, const void* __restrict__ be2,
    const u16* __restrict__ Q, const u16* __restrict__ Kd,
    float* __restrict__ scores, const int* __restrict__ flags)
{
  if (flags[1] != DT) return;
  __shared__ __align__(16) float wpk[128][16]; // {be1, We1[0..5][j], pad, We2[j][0..7]}
  __shared__ float b2s[8];
  const int tid = threadIdx.x;
  if (tid < 128) {
    int j = tid;
    wpk[j][0] = ldf<DT>(be1, j);
    #pragma unroll
    for (int d = 0; d < 6; ++d) wpk[j][1+d] = ldf<DT>(We1, d*128 + j);
    wpk[j][7] = 0.f;
    #pragma unroll
    for (int h = 0; h < 8; ++h) wpk[j][8+h] = ldf<DT>(We2, j*8 + h);
  }
  if (tid < 8) b2s[tid] = ldf<DT>(be2, tid);
  __syncthreads();

  const int gid = blockIdx.x * 256 + tid;
  if (gid >= N_EDGES/4) return;
  const int e0 = gid * 4;
  const int f64 = flags[0];

  float4 av[6];
  float* a = (float*)av;
  if (DT) {
    const float4* eg = (const float4*)ea + (size_t)gid*6;
    #pragma unroll
    for (int i = 0; i < 6; ++i) av[i] = eg[i];
  } else {
    const uint4* eg = (const uint4*)ea + (size_t)gid*3;
    uint4 v0 = eg[0], v1 = eg[1], v2 = eg[2];
    u32 d[12] = {v0.x,v0.y,v0.z,v0.w, v1.x,v1.y,v1.z,v1.w, v2.x,v2.y,v2.z,v2.w};
    #pragma unroll
    for (int idx = 0; idx < 24; ++idx)
      a[idx] = (idx & 1) ? hi16(d[idx >> 1]) : lo16(d[idx >> 1]);
  }

  float bias[4][8];
  #pragma unroll
  for (int t=0;t<4;++t)
    #pragma unroll
    for (int h=0;h<8;++h) bias[t][h] = b2s[h];

  for (int j = 0; j < 128; ++j) {
    const float4* wp = (const float4*)wpk[j];
    float4 p0 = wp[0], p1 = wp[1], p2 = wp[2], p3 = wp[3];
    #pragma unroll
    for (int t = 0; t < 4; ++t) {
      float h = p0.x + a[t*6+0]*p0.y + a[t*6+1]*p0.z + a[t*6+2]*p0.w
                     + a[t*6+3]*p1.x + a[t*6+4]*p1.y + a[t*6+5]*p1.z;
      float g = 0.5f * h * (1.0f + erff(h * 0.70710678118654752f)); // exact GELU
      bias[t][0] += g*p2.x; bias[t][1] += g*p2.y; bias[t][2] += g*p2.z; bias[t][3] += g*p2.w;
      bias[t][4] += g*p3.x; bias[t][5] += g*p3.y; bias[t][6] += g*p3.z; bias[t][7] += g*p3.w;
    }
  }

  #pragma unroll
  for (int t = 0; t < 4; ++t) {
    int e = e0 + t;
    int src = ld_src(ei, e, f64);
    int tgt = ld_tgt(ei, e, f64);
    const uint4* qr = (const uint4*)(Q  + (size_t)tgt*128);
    const uint4* kr = (const uint4*)(Kd + (size_t)src*128);
    float sc[8];
    #pragma unroll
    for (int hh = 0; hh < 8; ++hh) {
      uint4 qa = qr[hh*2], qb = qr[hh*2+1];
      uint4 ka = kr[hh*2], kb = kr[hh*2+1];
      float s = 0.f;
      s += lo16(qa.x)*lo16(ka.x) + hi16(qa.x)*hi16(ka.x);
      s += lo16(qa.y)*lo16(ka.y) + hi16(qa.y)*hi16(ka.y);
      s += lo16(qa.z)*lo16(ka.z) + hi16(qa.z)*hi16(ka.z);
      s += lo16(qa.w)*lo16(ka.w) + hi16(qa.w)*hi16(ka.w);
      s += lo16(qb.x)*lo16(kb.x) + hi16(qb.x)*hi16(kb.x);
      s += lo16(qb.y)*lo16(kb.y) + hi16(qb.y)*hi16(kb.y);
      s += lo16(qb.z)*lo16(kb.z) + hi16(qb.z)*hi16(kb.z);
      s += lo16(qb.w)*lo16(kb.w) + hi16(qb.w)*hi16(kb.w);
      sc[hh] = s * 0.25f + bias[t][hh];
    }
    float4* so = (float4*)(scores + (size_t)e*8);
    so[0] = make_float4(sc[0],sc[1],sc[2],sc[3]);
    so[1] = make_float4(sc[4],sc[5],sc[6],sc[7]);
  }
}

// ---------------- CSR build: histogram, scan, fill --------------------------
extern "C" __global__ __launch_bounds__(256) void hist_kernel(
    const int* __restrict__ ei, int* __restrict__ offs, const int* __restrict__ flags)
{
  int e = blockIdx.x*256 + threadIdx.x;
  if (e >= N_EDGES) return;
  int t = ld_tgt(ei, e, flags[0]);
  atomicAdd(&offs[t], 1);
}

extern "C" __global__ __launch_bounds__(1024) void scan1_kernel(
    int* __restrict__ offs, int* __restrict__ bsums)
{
  __shared__ int tmp[1024];
  int tid = threadIdx.x;
  int i = blockIdx.x*1024 + tid;
  int v = (i < N_NODES) ? offs[i] : 0;
  tmp[tid] = v;
  __syncthreads();
  for (int d = 1; d < 1024; d <<= 1) {
    int t = (tid >= d) ? tmp[tid-d] : 0;
    __syncthreads();
    tmp[tid] += t;
    __syncthreads();
  }
  if (i < N_NODES) offs[i] = tmp[tid] - v;   // block-exclusive
  if (tid == 1023) bsums[blockIdx.x] = tmp[1023];
}

extern "C" __global__ void scan2_kernel(int* __restrict__ bsums, int nb)
{
  if (threadIdx.x == 0 && blockIdx.x == 0) {
    int run = 0;
    for (int i = 0; i < nb; ++i) { int t = bsums[i]; bsums[i] = run; run += t; }
  }
}

extern "C" __global__ __launch_bounds__(1024) void scan3_kernel(
    int* __restrict__ offs, const int* __restrict__ bsums)
{
  int i = blockIdx.x*1024 + threadIdx.x;
  if (i < N_NODES) offs[i] += bsums[blockIdx.x];
}

// fill: consumes offs via atomicAdd; afterwards offs[t] == inclusive end of t
extern "C" __global__ __launch_bounds__(256) void fill_kernel(
    const int* __restrict__ ei, int* __restrict__ offs,
    int* __restrict__ edge_sorted, const int* __restrict__ flags)
{
  int e = blockIdx.x*256 + threadIdx.x;
  if (e >= N_EDGES) return;
  int t = ld_tgt(ei, e, flags[0]);
  int p = atomicAdd(&offs[t], 1);
  edge_sorted[p] = e;
}

// ------ K3: per-node softmax + attn-weight emit + weighted-V accumulate -----
// One wave per node; 4 nodes per block. No atomics, no __syncthreads.
extern "C" __global__ __launch_bounds__(256) void node_softmax_kernel(
    const int* __restrict__ ei, const int* __restrict__ offs_incl,
    const int* __restrict__ edge_sorted, const float* __restrict__ scores,
    const u16* __restrict__ Vd, void* __restrict__ dout,
    const int* __restrict__ flags)
{
  const int wid  = threadIdx.x >> 6;
  const int lane = threadIdx.x & 63;
  const int n = blockIdx.x*4 + wid;
  if (n >= N_NODES) return;
  const int f64 = flags[0], dt = flags[1];
  const int start = (n == 0) ? 0 : offs_incl[n-1];
  const int deg = offs_incl[n] - start;
  const int h = lane >> 3, j = lane & 7;

  // pass A: per-head max over this node's edges
  float m = -3.0e38f;
  for (int jj = j; jj < deg; jj += 8) {
    int e = edge_sorted[start + jj];
    m = fmaxf(m, scores[(size_t)e*8 + h]);
  }
  m = fmaxf(m, __shfl_xor(m, 1));
  m = fmaxf(m, __shfl_xor(m, 2));
  m = fmaxf(m, __shfl_xor(m, 4));
  // pass B: sum of exp
  float sum = 0.f;
  for (int jj = j; jj < deg; jj += 8) {
    int e = edge_sorted[start + jj];
    sum += __expf(scores[(size_t)e*8 + h] - m);
  }
  sum += __shfl_xor(sum, 1);
  sum += __shfl_xor(sum, 2);
  sum += __shfl_xor(sum, 4);
  float rsum = (deg > 0) ? 1.f / sum : 0.f;

  // pass C: emit normalized weights + accumulate w * V[src]
  float acc0 = 0.f, acc1 = 0.f;       // dims 2*lane, 2*lane+1
  const size_t attn_base = (size_t)N_NODES*128;
  const int srcl = (lane >> 3) * 8;   // head group for dims [2*lane, 2*lane+1]
  const int nch = (deg + 7) >> 3;
  for (int c = 0; c < nch; ++c) {
    int jj = c*8 + j;
    float w = 0.f;
    if (jj < deg) {
      int e = edge_sorted[start + jj];
      w = __expf(scores[(size_t)e*8 + h] - m) * rsum;
      if (dt) ((float*)dout)[attn_base + (size_t)e*8 + h] = w;
      else    ((u16*)dout)[attn_base + (size_t)e*8 + h] = (u16)f2bfbits(w);
    }
    int lim = deg - c*8; if (lim > 8) lim = 8;
    for (int t = 0; t < lim; ++t) {
      int e2 = edge_sorted[start + c*8 + t];       // uniform -> broadcast
      int s2 = ld_src(ei, e2, f64);
      u32 v = *(const u32*)(Vd + (size_t)s2*128 + lane*2);
      float wv = __shfl(w, srcl + t);
      acc0 += wv * lo16(v);
      acc1 += wv * hi16(v);
    }
  }
  // handoff row n as bf16 into d_out's row slot (stride 512B fp32-out / 256B bf16-out)
  u32 pair = f2bfbits(acc0) | (f2bfbits(acc1) << 16);
  size_t slot = dt ? ((size_t)n*128 + lane) : ((size_t)n*64 + lane);
  ((u32*)dout)[slot] = pair;
}

// ---------------- K4: output projection (bf16 handoff @ Wo + bo) ------------
template<int DT>
__global__ __launch_bounds__(256) void out_proj_t(
    const void* __restrict__ Wo, const void* __restrict__ bo,
    void* __restrict__ dout, const int* __restrict__ flags)
{
  if (flags[1] != DT) return;
  __shared__ float as_[64*129];
  const int tid = threadIdx.x;
  const int row0 = blockIdx.x * 64;
  {
    #pragma unroll
    for (int i = 0; i < 4; ++i) {
      int li = tid + i*256;           // 64 rows x 16 uint4 (bf16 rows)
      int r = li >> 4, q = li & 15;
      int gr = row0 + r;
      uint4 v = make_uint4(0,0,0,0);
      if (gr < N_NODES) {
        const uint4* rp = (const uint4*)((const u32*)dout + (DT ? (size_t)gr*128 : (size_t)gr*64));
        v = rp[q];
      }
      int base = r*129 + q*8;
      as_[base+0]=lo16(v.x); as_[base+1]=hi16(v.x);
      as_[base+2]=lo16(v.y); as_[base+3]=hi16(v.y);
      as_[base+4]=lo16(v.z); as_[base+5]=hi16(v.z);
      as_[base+6]=lo16(v.w); as_[base+7]=hi16(v.w);
    }
  }
  __syncthreads();
  const int cg = tid & 31;
  const int r0 = (tid >> 5) * 8;
  float acc[8][4];
  #pragma unroll
  for (int i=0;i<8;++i){ acc[i][0]=0.f; acc[i][1]=0.f; acc[i][2]=0.f; acc[i][3]=0.f; }

  for (int k = 0; k < 128; ++k) {
    float4 b;
    if (DT) {
      b = ((const float4*)Wo)[k*32 + cg];
    } else {
      uint2 t = ((const uint2*)Wo)[k*32 + cg];
      b = make_float4(lo16(t.x), hi16(t.x), lo16(t.y), hi16(t.y));
    }
    #pragma unroll
    for (int i = 0; i < 8; ++i) {
      float a = as_[(r0+i)*129 + k];
      acc[i][0] += a*b.x; acc[i][1] += a*b.y; acc[i][2] += a*b.z; acc[i][3] += a*b.w;
    }
  }
  float bb0 = ldf<DT>(bo, cg*4+0), bb1 = ldf<DT>(bo, cg*4+1);
  float bb2 = ldf<DT>(bo, cg*4+2), bb3 = ldf<DT>(bo, cg*4+3);
  #pragma unroll
  for (int i = 0; i < 8; ++i) {
    int gr = row0 + r0 + i;
    if (gr < N_NODES) {
      if (DT) {
        ((float4*)((float*)dout + (size_t)gr*128))[cg] =
            make_float4(acc[i][0]+bb0, acc[i][1]+bb1, acc[i][2]+bb2, acc[i][3]+bb3);
      } else {
        u32 p0 = f2bfbits(acc[i][0]+bb0) | (f2bfbits(acc[i][1]+bb1) << 16);
        u32 p1 = f2bfbits(acc[i][2]+bb2) | (f2bfbits(acc[i][3]+bb3) << 16);
        ((uint2*)((u16*)dout + (size_t)gr*128))[cg] = make_uint2(p0, p1);
      }
    }
  }
}

extern "C" void kernel_launch(void* const* d_in, const int* in_sizes, int n_in,
                              void* d_out, int out_size, void* d_ws, size_t ws_size,
                              hipStream_t stream)
{
  const void* x   = d_in[0];
  const int*  ei  = (const int*)d_in[1];
  const void* ea  = d_in[2];
  const void* Wq  = d_in[3];
  const void* Wk  = d_in[4];
  const void* Wv  = d_in[5];
  const void* We1 = d_in[6];
  const void* be1 = d_in[7];
  const void* We2 = d_in[8];
  const void* be2 = d_in[9];
  const void* Wo  = d_in[10];
  const void* bo  = d_in[11];

  // ws layout (83.6 MB total):
  char* ws = (char*)d_ws;
  int*   flags       = (int*)  ws;                 // 8 B (pad 4 KB)
  u16*   Vd          = (u16*)  (ws + 4096);        // 25.6 MB
  float* scores      = (float*)(ws + 25604096);    // 51.2 MB
  int*   offs        = (int*)  (ws + 76804096);    // N ints = 400 KB
  int*   bsums       = (int*)  (ws + 77204096);    // 98 ints
  int*   edge_sorted = (int*)  (ws + 77204992);    // E ints = 6.4 MB -> ends 83,604,992

  // Q/K staged in d_out's dead regions (bf16, 25.6 MB each). Both fit in the
  // final-out region (bf16-out: K spills into the attn region, dead until pass C).
  u16* Q  = (u16*)d_out;
  u16* Kd = Q + (size_t)N_NODES*128;

  detect_kernel<<<dim3(1), 64, 0, stream>>>(ei, (const u32*)x, flags);
  hipMemsetAsync(offs, 0, 400000, stream);

  qkv_gemm_t<0><<<dim3(1563,3), 256, 0, stream>>>(x, Wq, Wk, Wv, Q, Kd, Vd, flags);
  qkv_gemm_t<1><<<dim3(1563,3), 256, 0, stream>>>(x, Wq, Wk, Wv, Q, Kd, Vd, flags);
  edge_kernel_t<0><<<dim3(1563), 256, 0, stream>>>(ei, ea, We1, be1, We2, be2, Q, Kd, scores, flags);
  edge_kernel_t<1><<<dim3(1563), 256, 0, stream>>>(ei, ea, We1, be1, We2, be2, Q, Kd, scores, flags);

  hist_kernel <<<dim3(6250), 256, 0, stream>>>(ei, offs, flags);
  scan1_kernel<<<dim3(98), 1024, 0, stream>>>(offs, bsums);
  scan2_kernel<<<dim3(1), 64, 0, stream>>>(bsums, 98);
  scan3_kernel<<<dim3(98), 1024, 0, stream>>>(offs, bsums);
  fill_kernel <<<dim3(6250), 256, 0, stream>>>(ei, offs, edge_sorted, flags);

  node_softmax_kernel<<<dim3(25000), 256, 0, stream>>>(ei, offs, edge_sorted, scores, Vd, d_out, flags);

  out_proj_t<0><<<dim3(1563), 256, 0, stream>>>(Wo, bo, d_out, flags);
  out_proj_t<1><<<dim3(1563), 256, 0, stream>>>(Wo, bo, d_out, flags);
}

// Round 5
// 1052.537 us; speedup vs baseline: 2.1974x; 1.1485x over previous
//
#include <hip/hip_runtime.h>

#define N_NODES 100000
#define N_EDGES 1600000

typedef unsigned int u32;
typedef unsigned short u16;

__device__ __forceinline__ float bf2f(u16 u){ return __uint_as_float(((u32)u) << 16); }
__device__ __forceinline__ float lo16(u32 u){ return __uint_as_float(u << 16); }
__device__ __forceinline__ float hi16(u32 u){ return __uint_as_float(u & 0xffff0000u); }
__device__ __forceinline__ u32 f2bfbits(float f){
  u32 u = __float_as_uint(f);
  return (u + 0x7fffu + ((u >> 16) & 1u)) >> 16;
}

// DT=1: fp32 buffers, DT=0: bf16 buffers
template<int DT>
__device__ __forceinline__ float ldf(const void* p, size_t i){
  if (DT) return ((const float*)p)[i];
  else    return bf2f(((const u16*)p)[i]);
}

// flags[0]: 1 if edge_index is int64, 0 if int32
// flags[1]: 1 if float tensors are fp32, 0 if bf16
__device__ __forceinline__ int ld_src(const int* ei, int e, int f64){
  return f64 ? ei[2*(size_t)e] : ei[e];
}
__device__ __forceinline__ int ld_tgt(const int* ei, int e, int f64){
  return f64 ? ei[2*((size_t)N_EDGES + (size_t)e)] : ei[(size_t)N_EDGES + e];
}

extern "C" __global__ void detect_kernel(const int* __restrict__ ei,
                                         const u32* __restrict__ xw,
                                         int* __restrict__ flags)
{
  if (blockIdx.x == 0 && threadIdx.x == 0) {
    int any = 0;
    #pragma unroll
    for (int i = 0; i < 32; ++i) any |= ei[2*i + 1];
    flags[0] = (any == 0) ? 1 : 0;
    int weird = 0;
    for (int i = 0; i < 256; ++i) {
      u32 w = xw[i];
      float a = lo16(w), b = hi16(w);
      if (!(fabsf(a) < 1024.f)) weird++;
      if (!(fabsf(b) < 1024.f)) weird++;
    }
    flags[1] = (weird > 0) ? 1 : 0;
  }
}

// ---------------- K1: QKV projection (x @ W -> bf16) ------------------------
template<int DT>
__global__ __launch_bounds__(256) void qkv_gemm_t(
    const void* __restrict__ x, const void* __restrict__ Wq,
    const void* __restrict__ Wk, const void* __restrict__ Wv,
    u16* __restrict__ Q, u16* __restrict__ Kd, u16* __restrict__ Vd,
    const int* __restrict__ flags)
{
  if (flags[1] != DT) return;
  __shared__ float xs[64*129];
  const int tid = threadIdx.x;
  const int row0 = blockIdx.x * 64;
  const void* W = (blockIdx.y == 0) ? Wq : (blockIdx.y == 1) ? Wk : Wv;
  u16* Out = (blockIdx.y == 0) ? Q : (blockIdx.y == 1) ? Kd : Vd;

  if (DT) {
    const float4* xg = (const float4*)x;
    #pragma unroll
    for (int i = 0; i < 8; ++i) {
      int li = tid + i*256;           // 64 rows x 32 float4
      int r = li >> 5, c4 = li & 31;
      float4 v = make_float4(0.f,0.f,0.f,0.f);
      if (row0 + r < N_NODES) v = xg[(size_t)(row0 + r)*32 + c4];
      int base = r*129 + c4*4;
      xs[base] = v.x; xs[base+1] = v.y; xs[base+2] = v.z; xs[base+3] = v.w;
    }
  } else {
    const uint4* xg = (const uint4*)x;
    #pragma unroll
    for (int i = 0; i < 4; ++i) {
      int li = tid + i*256;           // 64 rows x 16 uint4
      int r = li >> 4, c8 = li & 15;
      uint4 v = make_uint4(0,0,0,0);
      if (row0 + r < N_NODES) v = xg[(size_t)(row0 + r)*16 + c8];
      int base = r*129 + c8*8;
      xs[base+0]=lo16(v.x); xs[base+1]=hi16(v.x);
      xs[base+2]=lo16(v.y); xs[base+3]=hi16(v.y);
      xs[base+4]=lo16(v.z); xs[base+5]=hi16(v.z);
      xs[base+6]=lo16(v.w); xs[base+7]=hi16(v.w);
    }
  }
  __syncthreads();

  const int cg = tid & 31;
  const int r0 = (tid >> 5) * 8;
  float acc[8][4];
  #pragma unroll
  for (int i=0;i<8;++i){ acc[i][0]=0.f; acc[i][1]=0.f; acc[i][2]=0.f; acc[i][3]=0.f; }

  for (int k = 0; k < 128; ++k) {
    float4 b;
    if (DT) {
      b = ((const float4*)W)[k*32 + cg];
    } else {
      uint2 t = ((const uint2*)W)[k*32 + cg];
      b = make_float4(lo16(t.x), hi16(t.x), lo16(t.y), hi16(t.y));
    }
    #pragma unroll
    for (int i = 0; i < 8; ++i) {
      float a = xs[(r0+i)*129 + k];
      acc[i][0] += a*b.x; acc[i][1] += a*b.y; acc[i][2] += a*b.z; acc[i][3] += a*b.w;
    }
  }
  #pragma unroll
  for (int i = 0; i < 8; ++i) {
    int gr = row0 + r0 + i;
    if (gr < N_NODES) {
      u32 p0 = f2bfbits(acc[i][0]) | (f2bfbits(acc[i][1]) << 16);
      u32 p1 = f2bfbits(acc[i][2]) | (f2bfbits(acc[i][3]) << 16);
      ((uint2*)(Out + (size_t)gr*128))[cg] = make_uint2(p0, p1);
    }
  }
}

// -------- K2a: per-edge MLP bias -> scores (pure compute, no gathers) -------
template<int DT>
__global__ __launch_bounds__(256) void bias_kernel_t(
    const void* __restrict__ ea,
    const void* __restrict__ We1, const void* __restrict__ be1,
    const void* __restrict__ We2, const void* __restrict__ be2,
    float* __restrict__ scores, const int* __restrict__ flags)
{
  if (flags[1] != DT) return;
  __shared__ __align__(16) float wpk[128][16]; // {be1, We1[0..5][j], pad, We2[j][0..7]}
  __shared__ float b2s[8];
  const int tid = threadIdx.x;
  if (tid < 128) {
    int j = tid;
    wpk[j][0] = ldf<DT>(be1, j);
    #pragma unroll
    for (int d = 0; d < 6; ++d) wpk[j][1+d] = ldf<DT>(We1, d*128 + j);
    wpk[j][7] = 0.f;
    #pragma unroll
    for (int h = 0; h < 8; ++h) wpk[j][8+h] = ldf<DT>(We2, j*8 + h);
  }
  if (tid < 8) b2s[tid] = ldf<DT>(be2, tid);
  __syncthreads();

  const int gid = blockIdx.x * 256 + tid;
  if (gid >= N_EDGES/4) return;
  const int e0 = gid * 4;

  float4 av[6];
  float* a = (float*)av;
  if (DT) {
    const float4* eg = (const float4*)ea + (size_t)gid*6;
    #pragma unroll
    for (int i = 0; i < 6; ++i) av[i] = eg[i];
  } else {
    const uint4* eg = (const uint4*)ea + (size_t)gid*3;
    uint4 v0 = eg[0], v1 = eg[1], v2 = eg[2];
    u32 d[12] = {v0.x,v0.y,v0.z,v0.w, v1.x,v1.y,v1.z,v1.w, v2.x,v2.y,v2.z,v2.w};
    #pragma unroll
    for (int idx = 0; idx < 24; ++idx)
      a[idx] = (idx & 1) ? hi16(d[idx >> 1]) : lo16(d[idx >> 1]);
  }

  float bias[4][8];
  #pragma unroll
  for (int t=0;t<4;++t)
    #pragma unroll
    for (int h=0;h<8;++h) bias[t][h] = b2s[h];

  for (int j = 0; j < 128; ++j) {
    const float4* wp = (const float4*)wpk[j];
    float4 p0 = wp[0], p1 = wp[1], p2 = wp[2], p3 = wp[3];
    #pragma unroll
    for (int t = 0; t < 4; ++t) {
      float h = p0.x + a[t*6+0]*p0.y + a[t*6+1]*p0.z + a[t*6+2]*p0.w
                     + a[t*6+3]*p1.x + a[t*6+4]*p1.y + a[t*6+5]*p1.z;
      float g = 0.5f * h * (1.0f + erff(h * 0.70710678118654752f)); // exact GELU
      bias[t][0] += g*p2.x; bias[t][1] += g*p2.y; bias[t][2] += g*p2.z; bias[t][3] += g*p2.w;
      bias[t][4] += g*p3.x; bias[t][5] += g*p3.y; bias[t][6] += g*p3.z; bias[t][7] += g*p3.w;
    }
  }

  #pragma unroll
  for (int t = 0; t < 4; ++t) {
    float4* so = (float4*)(scores + (size_t)(e0 + t)*8);
    so[0] = make_float4(bias[t][0],bias[t][1],bias[t][2],bias[t][3]);
    so[1] = make_float4(bias[t][4],bias[t][5],bias[t][6],bias[t][7]);
  }
}

// -------- K2b: QK dots (thread per edge-head, coalesced, high occupancy) ----
extern "C" __global__ __launch_bounds__(256) void qk_kernel(
    const int* __restrict__ ei, const u16* __restrict__ Q, const u16* __restrict__ Kd,
    float* __restrict__ scores, const int* __restrict__ flags)
{
  int i = blockIdx.x*256 + threadIdx.x;     // over E*8 = 12.8M exactly
  int e = i >> 3, h = i & 7;
  int f64 = flags[0];
  int src = ld_src(ei, e, f64);
  int tgt = ld_tgt(ei, e, f64);
  const uint4* qr = (const uint4*)(Q  + (size_t)tgt*128 + h*16);
  const uint4* kr = (const uint4*)(Kd + (size_t)src*128 + h*16);
  uint4 qa = qr[0], qb = qr[1];
  uint4 ka = kr[0], kb = kr[1];
  float s = 0.f;
  s += lo16(qa.x)*lo16(ka.x) + hi16(qa.x)*hi16(ka.x);
  s += lo16(qa.y)*lo16(ka.y) + hi16(qa.y)*hi16(ka.y);
  s += lo16(qa.z)*lo16(ka.z) + hi16(qa.z)*hi16(ka.z);
  s += lo16(qa.w)*lo16(ka.w) + hi16(qa.w)*hi16(ka.w);
  s += lo16(qb.x)*lo16(kb.x) + hi16(qb.x)*hi16(kb.x);
  s += lo16(qb.y)*lo16(kb.y) + hi16(qb.y)*hi16(kb.y);
  s += lo16(qb.z)*lo16(kb.z) + hi16(qb.z)*hi16(kb.z);
  s += lo16(qb.w)*lo16(kb.w) + hi16(qb.w)*hi16(kb.w);
  scores[i] += s * 0.25f;
}

// ---------------- CSR build: histogram, scan, fill --------------------------
extern "C" __global__ __launch_bounds__(256) void hist_kernel(
    const int* __restrict__ ei, int* __restrict__ offs, const int* __restrict__ flags)
{
  int e = blockIdx.x*256 + threadIdx.x;
  if (e >= N_EDGES) return;
  int t = ld_tgt(ei, e, flags[0]);
  atomicAdd(&offs[t], 1);
}

extern "C" __global__ __launch_bounds__(1024) void scan1_kernel(
    int* __restrict__ offs, int* __restrict__ bsums)
{
  __shared__ int tmp[1024];
  int tid = threadIdx.x;
  int i = blockIdx.x*1024 + tid;
  int v = (i < N_NODES) ? offs[i] : 0;
  tmp[tid] = v;
  __syncthreads();
  for (int d = 1; d < 1024; d <<= 1) {
    int t = (tid >= d) ? tmp[tid-d] : 0;
    __syncthreads();
    tmp[tid] += t;
    __syncthreads();
  }
  if (i < N_NODES) offs[i] = tmp[tid] - v;   // block-exclusive
  if (tid == 1023) bsums[blockIdx.x] = tmp[1023];
}

extern "C" __global__ void scan2_kernel(int* __restrict__ bsums, int nb)
{
  if (threadIdx.x == 0 && blockIdx.x == 0) {
    int run = 0;
    for (int i = 0; i < nb; ++i) { int t = bsums[i]; bsums[i] = run; run += t; }
  }
}

extern "C" __global__ __launch_bounds__(1024) void scan3_kernel(
    int* __restrict__ offs, const int* __restrict__ bsums)
{
  int i = blockIdx.x*1024 + threadIdx.x;
  if (i < N_NODES) offs[i] += bsums[blockIdx.x];
}

extern "C" __global__ __launch_bounds__(256) void fill_kernel(
    const int* __restrict__ ei, int* __restrict__ offs,
    int* __restrict__ edge_sorted, const int* __restrict__ flags)
{
  int e = blockIdx.x*256 + threadIdx.x;
  if (e >= N_EDGES) return;
  int t = ld_tgt(ei, e, flags[0]);
  int p = atomicAdd(&offs[t], 1);
  edge_sorted[p] = e;
}

// ------ K3: per-node online softmax + attn emit + weighted-V accumulate -----
// One wave per node; 4 nodes per block. No atomics.
extern "C" __global__ __launch_bounds__(256) void node_softmax_kernel(
    const int* __restrict__ ei, const int* __restrict__ offs_incl,
    const int* __restrict__ edge_sorted, const float* __restrict__ scores,
    const u16* __restrict__ Vd, void* __restrict__ dout,
    const int* __restrict__ flags)
{
  const int wid  = threadIdx.x >> 6;
  const int lane = threadIdx.x & 63;
  const int n = blockIdx.x*4 + wid;
  if (n >= N_NODES) return;
  const int f64 = flags[0], dt = flags[1];
  const int start = (n == 0) ? 0 : offs_incl[n-1];
  const int deg = offs_incl[n] - start;
  size_t slot = dt ? ((size_t)n*128 + lane) : ((size_t)n*64 + lane);
  if (deg == 0) { ((u32*)dout)[slot] = 0; return; }
  const int h = lane >> 3, j = lane & 7;
  const int srcl = h * 8;

  // online softmax over this node's edges (one gather pass)
  float m = -3.0e38f, s = 0.f;
  for (int jj = j; jj < deg; jj += 8) {
    int e = edge_sorted[start + jj];
    float v = scores[(size_t)e*8 + h];
    float mn = fmaxf(m, v);
    s = s * __expf(m - mn) + __expf(v - mn);
    m = mn;
  }
  #pragma unroll
  for (int d = 1; d < 8; d <<= 1) {
    float mo = __shfl_xor(m, d);
    float so = __shfl_xor(s, d);
    float mn = fmaxf(m, mo);
    s = s * __expf(m - mn) + so * __expf(mo - mn);
    m = mn;
  }
  float rsum = 1.f / s;

  // pass C: emit weights + accumulate w * V[src] with chunk-level prefetch
  float acc0 = 0.f, acc1 = 0.f;       // output dims 2*lane, 2*lane+1
  const size_t attn_base = (size_t)N_NODES*128;
  const int nch = (deg + 7) >> 3;
  for (int c = 0; c < nch; ++c) {
    int jj = c*8 + j;
    int ee = edge_sorted[start + (jj < deg ? jj : 0)];
    float w = 0.f;
    if (jj < deg) {
      w = __expf(scores[(size_t)ee*8 + h] - m) * rsum;
      if (dt) ((float*)dout)[attn_base + (size_t)ee*8 + h] = w;
      else    ((u16*)dout)[attn_base + (size_t)ee*8 + h] = (u16)f2bfbits(w);
    }
    int s_own = ld_src(ei, ee, f64);  // same across h-groups (depends only on j)
    int lim = deg - c*8; if (lim > 8) lim = 8;
    u32 vreg[8];
    #pragma unroll
    for (int t = 0; t < 8; ++t) {
      if (t < lim) {
        int s2 = __shfl(s_own, srcl + t);           // wave-uniform per t
        vreg[t] = *(const u32*)(Vd + (size_t)s2*128 + lane*2);
      }
    }
    #pragma unroll
    for (int t = 0; t < 8; ++t) {
      if (t < lim) {
        float wv = __shfl(w, srcl + t);
        acc0 += wv * lo16(vreg[t]);
        acc1 += wv * hi16(vreg[t]);
      }
    }
  }
  // handoff row n as bf16 into d_out's row slot
  ((u32*)dout)[slot] = f2bfbits(acc0) | (f2bfbits(acc1) << 16);
}

// ---------------- K4: output projection (bf16 handoff @ Wo + bo) ------------
template<int DT>
__global__ __launch_bounds__(256) void out_proj_t(
    const void* __restrict__ Wo, const void* __restrict__ bo,
    void* __restrict__ dout, const int* __restrict__ flags)
{
  if (flags[1] != DT) return;
  __shared__ float as_[64*129];
  const int tid = threadIdx.x;
  const int row0 = blockIdx.x * 64;
  {
    #pragma unroll
    for (int i = 0; i < 4; ++i) {
      int li = tid + i*256;           // 64 rows x 16 uint4 (bf16 rows)
      int r = li >> 4, q = li & 15;
      int gr = row0 + r;
      uint4 v = make_uint4(0,0,0,0);
      if (gr < N_NODES) {
        const uint4* rp = (const uint4*)((const u32*)dout + (DT ? (size_t)gr*128 : (size_t)gr*64));
        v = rp[q];
      }
      int base = r*129 + q*8;
      as_[base+0]=lo16(v.x); as_[base+1]=hi16(v.x);
      as_[base+2]=lo16(v.y); as_[base+3]=hi16(v.y);
      as_[base+4]=lo16(v.z); as_[base+5]=hi16(v.z);
      as_[base+6]=lo16(v.w); as_[base+7]=hi16(v.w);
    }
  }
  __syncthreads();
  const int cg = tid & 31;
  const int r0 = (tid >> 5) * 8;
  float acc[8][4];
  #pragma unroll
  for (int i=0;i<8;++i){ acc[i][0]=0.f; acc[i][1]=0.f; acc[i][2]=0.f; acc[i][3]=0.f; }

  for (int k = 0; k < 128; ++k) {
    float4 b;
    if (DT) {
      b = ((const float4*)Wo)[k*32 + cg];
    } else {
      uint2 t = ((const uint2*)Wo)[k*32 + cg];
      b = make_float4(lo16(t.x), hi16(t.x), lo16(t.y), hi16(t.y));
    }
    #pragma unroll
    for (int i = 0; i < 8; ++i) {
      float a = as_[(r0+i)*129 + k];
      acc[i][0] += a*b.x; acc[i][1] += a*b.y; acc[i][2] += a*b.z; acc[i][3] += a*b.w;
    }
  }
  float bb0 = ldf<DT>(bo, cg*4+0), bb1 = ldf<DT>(bo, cg*4+1);
  float bb2 = ldf<DT>(bo, cg*4+2), bb3 = ldf<DT>(bo, cg*4+3);
  #pragma unroll
  for (int i = 0; i < 8; ++i) {
    int gr = row0 + r0 + i;
    if (gr < N_NODES) {
      if (DT) {
        ((float4*)((float*)dout + (size_t)gr*128))[cg] =
            make_float4(acc[i][0]+bb0, acc[i][1]+bb1, acc[i][2]+bb2, acc[i][3]+bb3);
      } else {
        u32 p0 = f2bfbits(acc[i][0]+bb0) | (f2bfbits(acc[i][1]+bb1) << 16);
        u32 p1 = f2bfbits(acc[i][2]+bb2) | (f2bfbits(acc[i][3]+bb3) << 16);
        ((uint2*)((u16*)dout + (size_t)gr*128))[cg] = make_uint2(p0, p1);
      }
    }
  }
}

extern "C" void kernel_launch(void* const* d_in, const int* in_sizes, int n_in,
                              void* d_out, int out_size, void* d_ws, size_t ws_size,
                              hipStream_t stream)
{
  const void* x   = d_in[0];
  const int*  ei  = (const int*)d_in[1];
  const void* ea  = d_in[2];
  const void* Wq  = d_in[3];
  const void* Wk  = d_in[4];
  const void* Wv  = d_in[5];
  const void* We1 = d_in[6];
  const void* be1 = d_in[7];
  const void* We2 = d_in[8];
  const void* be2 = d_in[9];
  const void* Wo  = d_in[10];
  const void* bo  = d_in[11];

  // ws layout (83.6 MB total):
  char* ws = (char*)d_ws;
  int*   flags       = (int*)  ws;                 // 8 B (pad 4 KB)
  u16*   Vd          = (u16*)  (ws + 4096);        // 25.6 MB
  float* scores      = (float*)(ws + 25604096);    // 51.2 MB
  int*   offs        = (int*)  (ws + 76804096);    // N ints = 400 KB
  int*   bsums       = (int*)  (ws + 77204096);    // 98 ints
  int*   edge_sorted = (int*)  (ws + 77204992);    // E ints = 6.4 MB -> ends 83,604,992

  // Q/K staged in d_out's dead regions (bf16, 25.6 MB each).
  u16* Q  = (u16*)d_out;
  u16* Kd = Q + (size_t)N_NODES*128;

  detect_kernel<<<dim3(1), 64, 0, stream>>>(ei, (const u32*)x, flags);
  hipMemsetAsync(offs, 0, 400000, stream);

  qkv_gemm_t<0><<<dim3(1563,3), 256, 0, stream>>>(x, Wq, Wk, Wv, Q, Kd, Vd, flags);
  qkv_gemm_t<1><<<dim3(1563,3), 256, 0, stream>>>(x, Wq, Wk, Wv, Q, Kd, Vd, flags);

  bias_kernel_t<0><<<dim3(1563), 256, 0, stream>>>(ea, We1, be1, We2, be2, scores, flags);
  bias_kernel_t<1><<<dim3(1563), 256, 0, stream>>>(ea, We1, be1, We2, be2, scores, flags);
  qk_kernel<<<dim3(50000), 256, 0, stream>>>(ei, Q, Kd, scores, flags);

  hist_kernel <<<dim3(6250), 256, 0, stream>>>(ei, offs, flags);
  scan1_kernel<<<dim3(98), 1024, 0, stream>>>(offs, bsums);
  scan2_kernel<<<dim3(1), 64, 0, stream>>>(bsums, 98);
  scan3_kernel<<<dim3(98), 1024, 0, stream>>>(offs, bsums);
  fill_kernel <<<dim3(6250), 256, 0, stream>>>(ei, offs, edge_sorted, flags);

  node_softmax_kernel<<<dim3(25000), 256, 0, stream>>>(ei, offs, edge_sorted, scores, Vd, d_out, flags);

  out_proj_t<0><<<dim3(1563), 256, 0, stream>>>(Wo, bo, d_out, flags);
  out_proj_t<1><<<dim3(1563), 256, 0, stream>>>(Wo, bo, d_out, flags);
}